// Round 8
// baseline (243.088 us; speedup 1.0000x reference)
//
#include <hip/hip_runtime.h>
#include <math.h>

#define CSTRIDE (512 * 512)

// numpy generic-strided einsum inner loop (scalar C, no SIMD, no FMA):
// accum += c[q]*v[q], q ascending, 64-deep sequential chain, each term
// mul-rounded then add-rounded. REQUIRED bit-exact: feeds rintf() quantization.
__device__ __forceinline__ float chain_dot64_nofma(const float* __restrict__ c,
                                                   const float* __restrict__ v)
{
#pragma clang fp contract(off)
    float s = 0.0f;
#pragma unroll
    for (int q = 0; q < 64; ++q) s = s + c[q] * v[q];
    return s;
}

// R8: R1 mapping (lane=block, wave=j-range: keeps C-row + Q wave-uniform ->
// SGPR operands) but recon stays in REGISTERS and the output mix accumulates
// across the channel loop (output = linear in recon channels). Deletes the
// recon LDS writes (48/thread), output LDS reads (48/thread), and 4 of 11
// barriers. R7 falsified round-imbalance; remaining stall is barrier/LDS-phase
// convergence, which this attacks directly.
__global__ __launch_bounds__(256, 3)
void jpeg_kernel(const float* __restrict__ img,
                 const float* __restrict__ rgb2yuv,
                 const float* __restrict__ yuv2rgb,
                 const float* __restrict__ dctC,
                 const float* __restrict__ qlum,
                 const float* __restrict__ qchrom,
                 float* __restrict__ out)
{
#pragma clang fp contract(off)
    __shared__ float V[3][4096];   // 48 KB: per-channel (q=x*8+y)[64] x block[64]

    const int tid  = threadIdx.x;
    const int lane = tid & 63;                                        // block index
    const int wv   = tid >> 6;
    const int p0u  = __builtin_amdgcn_readfirstlane(wv * 16);         // wave's p range

    const int b  = blockIdx.x >> 6;
    const int y0 = (blockIdx.x & 63) << 3;
    const size_t base0 = (size_t)b * 3 * CSTRIDE + (size_t)y0 * 512;

    const float r00 = rgb2yuv[0], r01 = rgb2yuv[1], r02 = rgb2yuv[2];
    const float r10 = rgb2yuv[3], r11 = rgb2yuv[4], r12 = rgb2yuv[5];
    const float r20 = rgb2yuv[6], r21 = rgb2yuv[7], r22 = rgb2yuv[8];

    // Phase 1: coalesced RGB loads; numpy color loop model (no FMA) — EXACT
#pragma unroll
    for (int i = 0; i < 4; ++i) {
        const size_t f4 = 4 * (size_t)(tid + 256 * i);
        const float4 R4 = *(const float4*)(img + base0 + f4);
        const float4 G4 = *(const float4*)(img + base0 + CSTRIDE + f4);
        const float4 B4 = *(const float4*)(img + base0 + 2 * CSTRIDE + f4);
        const float* rp = (const float*)&R4;
        const float* gp = (const float*)&G4;
        const float* bp = (const float*)&B4;
#pragma unroll
        for (int jj = 0; jj < 4; ++jj) {
            const int flat = 4 * (tid + 256 * i) + jj;   // x*512 + col
            const int w = flat & 511, x = flat >> 9;
            const int idx = ((x << 3) + (w & 7)) * 64 + (w >> 3);
            const float r_ = rp[jj], g_ = gp[jj], b_ = bp[jj];
            float t;
            t = (r00 * r_ + r01 * g_) + r02 * b_;  V[0][idx] = t * 255.0f - 128.0f;
            t = (r10 * r_ + r11 * g_) + r12 * b_;  V[1][idx] = t * 255.0f - 128.0f;
            t = (r20 * r_ + r21 * g_) + r22 * b_;  V[2][idx] = t * 255.0f - 128.0f;
        }
    }
    __syncthreads();

    // Inverse-DCT row constants for this wave's two spatial rows x = 2*wv, 2*wv+1.
    // dctC[x*512 + u*8] = M[x][u] * M[0][0]; 1/M[0][0] = 2.828427...
    const int xb = __builtin_amdgcn_readfirstlane(wv * 2);
    float mrow[2][8];
#pragma unroll
    for (int k = 0; k < 2; ++k)
#pragma unroll
        for (int u = 0; u < 8; ++u)
            mrow[k][u] = dctC[(size_t)(xb + k) * 512 + u * 8] * 2.82842712474619f;

    // Column-pass constants (compile-time -> folds to literals):
    // MT[r][c] = 0.5*cos((2c+1)*r*pi/16), row 0 scaled by 1/sqrt(2)
    const float MT[8][8] = {
        { 0.353553391f,  0.353553391f,  0.353553391f,  0.353553391f,  0.353553391f,  0.353553391f,  0.353553391f,  0.353553391f},
        { 0.490392640f,  0.415734806f,  0.277785117f,  0.097545161f, -0.097545161f, -0.277785117f, -0.415734806f, -0.490392640f},
        { 0.461939766f,  0.191341716f, -0.191341716f, -0.461939766f, -0.461939766f, -0.191341716f,  0.191341716f,  0.461939766f},
        { 0.415734806f, -0.097545161f, -0.490392640f, -0.277785117f,  0.277785117f,  0.490392640f,  0.097545161f, -0.415734806f},
        { 0.353553391f, -0.353553391f, -0.353553391f,  0.353553391f,  0.353553391f, -0.353553391f, -0.353553391f,  0.353553391f},
        { 0.277785117f, -0.490392640f,  0.097545161f,  0.415734806f, -0.415734806f, -0.097545161f,  0.490392640f, -0.277785117f},
        { 0.191341716f, -0.461939766f,  0.461939766f, -0.191341716f, -0.191341716f,  0.461939766f, -0.461939766f,  0.191341716f},
        { 0.097545161f, -0.277785117f,  0.415734806f, -0.490392640f,  0.490392640f, -0.415734806f,  0.277785117f, -0.097545161f}};

    // Output-mix coefficients (inverse side: folding /255 + 128 is order-free)
    const float s255 = 1.0f / 255.0f;
    const float c00 = yuv2rgb[0] * s255, c01 = yuv2rgb[1] * s255, c02 = yuv2rgb[2] * s255;
    const float c10 = yuv2rgb[3] * s255, c11 = yuv2rgb[4] * s255, c12 = yuv2rgb[5] * s255;
    const float c20 = yuv2rgb[6] * s255, c21 = yuv2rgb[7] * s255, c22 = yuv2rgb[8] * s255;
    const float k0 = (yuv2rgb[0] + yuv2rgb[1] + yuv2rgb[2]) * (128.0f / 255.0f);
    const float k1 = (yuv2rgb[3] + yuv2rgb[4] + yuv2rgb[5]) * (128.0f / 255.0f);
    const float k2 = (yuv2rgb[6] + yuv2rgb[7] + yuv2rgb[8]) * (128.0f / 255.0f);

    // Output accumulators: this thread's 16 pixels x 3 output channels.
    float accR[16], accG[16], accB[16];
#pragma unroll
    for (int j = 0; j < 16; ++j) { accR[j] = k0; accG[j] = k1; accB[j] = k2; }

    for (int c = 0; c < 3; ++c) {
        float* Vc = V[c];
        // per-input-channel output coefficients (uniform -> s_cselect)
        const float cR = (c == 0) ? c00 : ((c == 1) ? c01 : c02);
        const float cG = (c == 0) ? c10 : ((c == 1) ? c11 : c12);
        const float cB = (c == 0) ? c20 : ((c == 1) ? c21 : c22);

        // preload this thread's block column (64 VGPRs)
        float v[64];
#pragma unroll
        for (int q = 0; q < 64; ++q) v[q] = Vc[q * 64 + lane];
        __syncthreads();   // B1: all preloads done before dq overwrites Vc

        // forward DCT: 64-deep sequential no-FMA chain, quantize/dequant — EXACT
        const float* qtab = (c == 0) ? qlum : qchrom;
        for (int j = 0; j < 16; ++j) {
            const float* Crow = dctC + (size_t)(p0u + j) * 64;  // uniform -> s_load
            const float d  = chain_dot64_nofma(Crow, v);
            const float qv = qtab[p0u + j];
            const float dq = rintf(d / qv) * qv;   // fp32 div, half-even, fp32 mul
            Vc[(p0u + j) * 64 + lane] = dq;
        }
        __syncthreads();   // B2: dq visible for cross-wave column reads

        // Inverse DCT, separable + FMA (numerically free past quantization):
        //   t[u][y] = sum_v MT[y][v]*d[u][v];  r[x][y] = sum_u M[x][u]*t[u][y]
        float t[64];
#pragma unroll
        for (int u = 0; u < 8; ++u) {
            float du[8];
#pragma unroll
            for (int q = 0; q < 8; ++q) du[q] = Vc[(u * 8 + q) * 64 + lane];
#pragma unroll
            for (int y = 0; y < 8; ++y) {
                float s = MT[y][0] * du[0];
#pragma unroll
                for (int q = 1; q < 8; ++q) s = fmaf(MT[y][q], du[q], s);
                t[u * 8 + y] = s;
            }
        }

        // Row pass -> accumulate straight into the output mix (NO LDS write,
        // NO barrier: nothing reads Vc again; channel c+1 preloads V[c+1]).
#pragma unroll
        for (int j = 0; j < 16; ++j) {
            const int k = j >> 3, y = j & 7;     // p = p0u+j = (xb+k)*8 + y
            float s = mrow[k][0] * t[y];
#pragma unroll
            for (int u = 1; u < 8; ++u) s = fmaf(mrow[k][u], t[u * 8 + y], s);
            accR[j] = fmaf(cR, s, accR[j]);
            accG[j] = fmaf(cG, s, accG[j]);
            accB[j] = fmaf(cB, s, accB[j]);
        }
    }

    // Direct stores from registers. Thread owns pixel rows x=2wv+g (g=0,1),
    // cols 8*lane..8*lane+7: two float4 per row per channel (32B-strided
    // across lanes; j/j+4 pair covers both halves of each 32B sector -> L2
    // merges; WRITE_SIZE is the tripwire for this assumption).
#pragma unroll
    for (int g = 0; g < 2; ++g) {
        const size_t rb = base0 + (size_t)(2 * wv + g) * 512 + 8 * (size_t)lane;
        float4 o;
        o.x = accR[g*8+0]; o.y = accR[g*8+1]; o.z = accR[g*8+2]; o.w = accR[g*8+3];
        *(float4*)(out + rb) = o;
        o.x = accR[g*8+4]; o.y = accR[g*8+5]; o.z = accR[g*8+6]; o.w = accR[g*8+7];
        *(float4*)(out + rb + 4) = o;
        o.x = accG[g*8+0]; o.y = accG[g*8+1]; o.z = accG[g*8+2]; o.w = accG[g*8+3];
        *(float4*)(out + CSTRIDE + rb) = o;
        o.x = accG[g*8+4]; o.y = accG[g*8+5]; o.z = accG[g*8+6]; o.w = accG[g*8+7];
        *(float4*)(out + CSTRIDE + rb + 4) = o;
        o.x = accB[g*8+0]; o.y = accB[g*8+1]; o.z = accB[g*8+2]; o.w = accB[g*8+3];
        *(float4*)(out + 2 * CSTRIDE + rb) = o;
        o.x = accB[g*8+4]; o.y = accB[g*8+5]; o.z = accB[g*8+6]; o.w = accB[g*8+7];
        *(float4*)(out + 2 * CSTRIDE + rb + 4) = o;
    }
}

extern "C" void kernel_launch(void* const* d_in, const int* in_sizes, int n_in,
                              void* d_out, int out_size, void* d_ws, size_t ws_size,
                              hipStream_t stream) {
    const float* img = (const float*)d_in[0];
    const float* r2y = (const float*)d_in[1];
    const float* y2r = (const float*)d_in[2];
    const float* C   = (const float*)d_in[3];
    const float* ql  = (const float*)d_in[4];
    const float* qc  = (const float*)d_in[5];
    float* o = (float*)d_out;

    jpeg_kernel<<<dim3(16 * 64), dim3(256), 0, stream>>>(img, r2y, y2r, C, ql, qc, o);
}

// Round 9
// 156.487 us; speedup vs baseline: 1.5534x; 1.5534x over previous
//
#include <hip/hip_runtime.h>
#include <math.h>

#define CSTRIDE (512 * 512)

// Two INDEPENDENT numpy chains (rows A and B) interleaved for ILP.
// Each chain is the exact scalar semantic: accum += c[q]*v[q], q ascending,
// mul-rounded then add-rounded, 64-deep sequential. The chains never mix —
// bit-exact per row — but give the scheduler a second dependency stream to
// fill the ~4cy add-latency gaps (R1 ledger: VALUBusy 53% = latency-bound).
__device__ __forceinline__ void chain_dot64_nofma_x2(const float* __restrict__ cA,
                                                     const float* __restrict__ cB,
                                                     const float* __restrict__ v,
                                                     float& outA, float& outB)
{
#pragma clang fp contract(off)
    float sA = 0.0f, sB = 0.0f;
#pragma unroll
    for (int q = 0; q < 64; ++q) {
        sA = sA + cA[q] * v[q];
        sB = sB + cB[q] * v[q];
    }
    outA = sA; outB = sB;
}

__global__ __launch_bounds__(256, 3)
void jpeg_kernel(const float* __restrict__ img,
                 const float* __restrict__ rgb2yuv,
                 const float* __restrict__ yuv2rgb,
                 const float* __restrict__ dctC,
                 const float* __restrict__ qlum,
                 const float* __restrict__ qchrom,
                 float* __restrict__ out)
{
#pragma clang fp contract(off)
    __shared__ float V[3][4096];   // 48 KB: per-channel (q=x*8+y)[64] x block[64]

    const int tid  = threadIdx.x;
    const int lane = tid & 63;                                        // block index
    const int wv   = tid >> 6;
    const int p0u  = __builtin_amdgcn_readfirstlane(wv * 16);         // wave's p range

    const int b  = blockIdx.x >> 6;
    const int y0 = (blockIdx.x & 63) << 3;
    const size_t base0 = (size_t)b * 3 * CSTRIDE + (size_t)y0 * 512;

    const float r00 = rgb2yuv[0], r01 = rgb2yuv[1], r02 = rgb2yuv[2];
    const float r10 = rgb2yuv[3], r11 = rgb2yuv[4], r12 = rgb2yuv[5];
    const float r20 = rgb2yuv[6], r21 = rgb2yuv[7], r22 = rgb2yuv[8];

    // Phase 1: coalesced RGB loads; numpy color loop model (no FMA) — EXACT
#pragma unroll
    for (int i = 0; i < 4; ++i) {
        const size_t f4 = 4 * (size_t)(tid + 256 * i);
        const float4 R4 = *(const float4*)(img + base0 + f4);
        const float4 G4 = *(const float4*)(img + base0 + CSTRIDE + f4);
        const float4 B4 = *(const float4*)(img + base0 + 2 * CSTRIDE + f4);
        const float* rp = (const float*)&R4;
        const float* gp = (const float*)&G4;
        const float* bp = (const float*)&B4;
#pragma unroll
        for (int jj = 0; jj < 4; ++jj) {
            const int flat = 4 * (tid + 256 * i) + jj;   // x*512 + col
            const int w = flat & 511, x = flat >> 9;
            const int idx = ((x << 3) + (w & 7)) * 64 + (w >> 3);
            const float r_ = rp[jj], g_ = gp[jj], b_ = bp[jj];
            float t;
            t = (r00 * r_ + r01 * g_) + r02 * b_;  V[0][idx] = t * 255.0f - 128.0f;
            t = (r10 * r_ + r11 * g_) + r12 * b_;  V[1][idx] = t * 255.0f - 128.0f;
            t = (r20 * r_ + r21 * g_) + r22 * b_;  V[2][idx] = t * 255.0f - 128.0f;
        }
    }
    __syncthreads();

    // Inverse-DCT row constants for this wave's two spatial rows x = 2*wv, 2*wv+1.
    // dctC[x*512 + u*8] = M[x][u] * M[0][0]; 1/M[0][0] = 2.828427...
    const int xb = __builtin_amdgcn_readfirstlane(wv * 2);
    float mrow[2][8];
#pragma unroll
    for (int k = 0; k < 2; ++k)
#pragma unroll
        for (int u = 0; u < 8; ++u)
            mrow[k][u] = dctC[(size_t)(xb + k) * 512 + u * 8] * 2.82842712474619f;

    // Column-pass constants (compile-time -> folds to literals):
    // MT[r][c] = 0.5*cos((2c+1)*r*pi/16), row 0 scaled by 1/sqrt(2)
    const float MT[8][8] = {
        { 0.353553391f,  0.353553391f,  0.353553391f,  0.353553391f,  0.353553391f,  0.353553391f,  0.353553391f,  0.353553391f},
        { 0.490392640f,  0.415734806f,  0.277785117f,  0.097545161f, -0.097545161f, -0.277785117f, -0.415734806f, -0.490392640f},
        { 0.461939766f,  0.191341716f, -0.191341716f, -0.461939766f, -0.461939766f, -0.191341716f,  0.191341716f,  0.461939766f},
        { 0.415734806f, -0.097545161f, -0.490392640f, -0.277785117f,  0.277785117f,  0.490392640f,  0.097545161f, -0.415734806f},
        { 0.353553391f, -0.353553391f, -0.353553391f,  0.353553391f,  0.353553391f, -0.353553391f, -0.353553391f,  0.353553391f},
        { 0.277785117f, -0.490392640f,  0.097545161f,  0.415734806f, -0.415734806f, -0.097545161f,  0.490392640f, -0.277785117f},
        { 0.191341716f, -0.461939766f,  0.461939766f, -0.191341716f, -0.191341716f,  0.461939766f, -0.461939766f,  0.191341716f},
        { 0.097545161f, -0.277785117f,  0.415734806f, -0.490392640f,  0.490392640f, -0.415734806f,  0.277785117f, -0.097545161f}};

    for (int c = 0; c < 3; ++c) {
        float* Vc = V[c];

        // preload this thread's block column (64 VGPRs)
        float v[64];
#pragma unroll
        for (int q = 0; q < 64; ++q) v[q] = Vc[q * 64 + lane];
        __syncthreads();   // all waves preloaded before we overwrite V[c]

        // forward DCT: 2 independent exact chains in flight (rows j, j+1)
        const float* qtab = (c == 0) ? qlum : qchrom;
        for (int j = 0; j < 16; j += 2) {
            const float* CrowA = dctC + (size_t)(p0u + j) * 64;      // uniform
            const float* CrowB = dctC + (size_t)(p0u + j + 1) * 64;  // uniform
            float dA, dB;
            chain_dot64_nofma_x2(CrowA, CrowB, v, dA, dB);
            const float qA = qtab[p0u + j];
            const float qB = qtab[p0u + j + 1];
            const float dqA = rintf(dA / qA) * qA;   // fp32 div, half-even, fp32 mul
            const float dqB = rintf(dB / qB) * qB;
            Vc[(p0u + j) * 64 + lane]     = dqA;
            Vc[(p0u + j + 1) * 64 + lane] = dqB;
        }
        __syncthreads();

        // Inverse DCT, separable + FMA (numerically free past quantization):
        //   t[u][y] = sum_v MT[y][v] * d[u][v];  r[x][y] = sum_u M[x][u] * t[u][y]
        float t[64];
#pragma unroll
        for (int u = 0; u < 8; ++u) {
            float du[8];
#pragma unroll
            for (int q = 0; q < 8; ++q) du[q] = Vc[(u * 8 + q) * 64 + lane];
#pragma unroll
            for (int y = 0; y < 8; ++y) {
                float s = MT[y][0] * du[0];
#pragma unroll
                for (int q = 1; q < 8; ++q) s = fmaf(MT[y][q], du[q], s);
                t[u * 8 + y] = s;
            }
        }
        __syncthreads();   // everyone done reading Vc before recon overwrite

#pragma unroll
        for (int j = 0; j < 16; ++j) {
            const int k = j >> 3, y = j & 7;     // p = p0u+j = (xb+k)*8 + y
            float s = mrow[k][0] * t[y];
#pragma unroll
            for (int u = 1; u < 8; ++u) s = fmaf(mrow[k][u], t[u * 8 + y], s);
            Vc[(p0u + j) * 64 + lane] = s;
        }
        // writes re-read only after the next barrier
    }
    __syncthreads();

    // Output: fold yuv2rgb and (x+128)/255 into 3 FMAs per pixel-channel,
    // read V in DCT layout (2-way LDS, free), store coalesced float4 (R1 path).
    const float s255 = 1.0f / 255.0f;
    const float c00 = yuv2rgb[0] * s255, c01 = yuv2rgb[1] * s255, c02 = yuv2rgb[2] * s255;
    const float c10 = yuv2rgb[3] * s255, c11 = yuv2rgb[4] * s255, c12 = yuv2rgb[5] * s255;
    const float c20 = yuv2rgb[6] * s255, c21 = yuv2rgb[7] * s255, c22 = yuv2rgb[8] * s255;
    const float k0 = (yuv2rgb[0] + yuv2rgb[1] + yuv2rgb[2]) * (128.0f / 255.0f);
    const float k1 = (yuv2rgb[3] + yuv2rgb[4] + yuv2rgb[5]) * (128.0f / 255.0f);
    const float k2 = (yuv2rgb[6] + yuv2rgb[7] + yuv2rgb[8]) * (128.0f / 255.0f);

#pragma unroll
    for (int i = 0; i < 4; ++i) {
        float4 o0, o1, o2;
        float* q0 = (float*)&o0; float* q1 = (float*)&o1; float* q2 = (float*)&o2;
#pragma unroll
        for (int jj = 0; jj < 4; ++jj) {
            const int flat = 4 * (tid + 256 * i) + jj;
            const int w = flat & 511, x = flat >> 9;
            const int cell = ((x << 3) + (w & 7)) * 64 + (w >> 3);   // 2-way LDS (free)
            const float Yv = V[0][cell], Uv = V[1][cell], Wv = V[2][cell];
            q0[jj] = fmaf(c00, Yv, fmaf(c01, Uv, fmaf(c02, Wv, k0)));
            q1[jj] = fmaf(c10, Yv, fmaf(c11, Uv, fmaf(c12, Wv, k1)));
            q2[jj] = fmaf(c20, Yv, fmaf(c21, Uv, fmaf(c22, Wv, k2)));
        }
        const size_t f4 = 4 * (size_t)(tid + 256 * i);
        *(float4*)(out + base0 + f4)                = o0;
        *(float4*)(out + base0 + CSTRIDE + f4)      = o1;
        *(float4*)(out + base0 + 2 * CSTRIDE + f4)  = o2;
    }
}

extern "C" void kernel_launch(void* const* d_in, const int* in_sizes, int n_in,
                              void* d_out, int out_size, void* d_ws, size_t ws_size,
                              hipStream_t stream) {
    const float* img = (const float*)d_in[0];
    const float* r2y = (const float*)d_in[1];
    const float* y2r = (const float*)d_in[2];
    const float* C   = (const float*)d_in[3];
    const float* ql  = (const float*)d_in[4];
    const float* qc  = (const float*)d_in[5];
    float* o = (float*)d_out;

    jpeg_kernel<<<dim3(16 * 64), dim3(256), 0, stream>>>(img, r2y, y2r, C, ql, qc, o);
}